// Round 15
// baseline (110.625 us; speedup 1.0000x reference)
//
#include <hip/hip_runtime.h>
#include <math.h>

// Problem constants: B=4, S=2048, D=512, H=8, DH=64
typedef __attribute__((ext_vector_type(8))) short bf8;
typedef __attribute__((ext_vector_type(4))) float f4;
typedef __attribute__((ext_vector_type(8))) unsigned short u16v8;
typedef __attribute__((ext_vector_type(4))) unsigned short u16v4;

#define MFMA(a, b, c) __builtin_amdgcn_mfma_f32_16x16x32_bf16((a), (b), (c), 0, 0, 0)
#define GLD16(src, dst)                                                        \
  __builtin_amdgcn_global_load_lds((const __attribute__((address_space(1))) void*)(src), \
                                   (__attribute__((address_space(3))) void*)(dst), 16, 0, 0)

__device__ __forceinline__ unsigned short f2bf(float f) {
  union { float f; unsigned u; } v; v.f = f;
  unsigned r = v.u + 0x7FFFu + ((v.u >> 16) & 1u);  // RNE
  return (unsigned short)(r >> 16);
}

__device__ __forceinline__ unsigned cvtpk(float lo, float hi) {
  unsigned r;
  asm("v_cvt_pk_bf16_f32 %0, %1, %2" : "=v"(r) : "v"(lo), "v"(hi));
  return r;
}

__device__ __forceinline__ float exp2a(float x) {  // v_exp_f32 = 2^x
  float r;
  asm("v_exp_f32 %0, %1" : "=v"(r) : "v"(x));
  return r;
}

// ---------- weight prep: transpose + bf16, fold W_gen_S (and log2e) into W_K ----------
__global__ __launch_bounds__(256) void k_prep(
    const float* __restrict__ WQ, const float* __restrict__ WK,
    const float* __restrict__ WV, const float* __restrict__ Wg,
    const float* __restrict__ Wmh,
    unsigned short* __restrict__ BtQ, unsigned short* __restrict__ BtK,
    unsigned short* __restrict__ BtV, unsigned short* __restrict__ BtM) {
  int id = blockIdx.x * 256 + threadIdx.x;  // 512*512 threads
  int k = id & 511, n = id >> 9;
  BtQ[n * 512 + k] = f2bf(WQ[k * 512 + n]);
  BtV[n * 512 + k] = f2bf(WV[k * 512 + n]);
  BtM[n * 512 + k] = f2bf(Wmh[k * 512 + n]);
  int h = n >> 6, e = n & 63;
  const float* wk = WK + k * 512 + h * 64;
  float s = 0.f;
#pragma unroll
  for (int c = 0; c < 64; ++c) s = fmaf(wk[c], Wg[c * 64 + e], s);
  BtK[n * 512 + k] = f2bf(s * 1.44269504088896f);  // fold log2(e): attn uses exp2
}

// ---------- GEMM body: C[M,512] = A[M,512] @ Bt[512,512]^T ----------
// BK=64, LDS [128][64] with XOR swizzle colb ^= (row&7)<<4 on the read side;
// A: if AF32, reg-staged f32 + cvt_pk -> ds_write to the linear slot (fused cvt);
//    else global_load_lds direct. B always global_load_lds; source pre-permuted.
// mode 0: bf16 row-major; 1: f32 row-major; 2: bf16 transposed-per-head (Vt),
//         with key-axis sigma^-1 pre-permutation (attn PV slot map).
template <bool AF32>
__device__ __forceinline__ void gemm_body(const void* __restrict__ Av,
                                          const unsigned short* __restrict__ Bt,
                                          void* __restrict__ C, int mode) {
  constexpr int KD = 512, N = 512;
  __shared__ unsigned short As[128 * 64];
  __shared__ unsigned short Bs[128 * 64];
  const int t = threadIdx.x;
  const int lane = t & 63;
  const int w = t >> 6, wm = w >> 1, wn = w & 1;  // 2x2 wave grid, 64x64 per wave
  const int i = lane & 15, g = lane >> 4;
  const int bm = blockIdx.x, bn = blockIdx.y;

  f4 acc[4][4] = {};
  // staging: chunk c covers rows c*32 + (t>>3); col bytes (t&7)*16, source inverse-swizzled
  const int srow = t >> 3;
  const int scolb = (t & 7) * 16;
  const int acolb = scolb ^ ((srow & 7) << 4);
  const float* Ab32 = (const float*)Av + (size_t)(bm * 128 + srow) * KD + (acolb >> 1);
  const unsigned short* Ab16 = (const unsigned short*)Av + (size_t)(bm * 128 + srow) * KD + (acolb >> 1);
  const unsigned short* Bb = Bt + (size_t)(bn * 128 + srow) * KD + (acolb >> 1);
  char* lA = (char*)As + t * 16;
  char* lB = (char*)Bs + t * 16;

  for (int kt = 0; kt < KD; kt += 64) {
    __syncthreads();
    if constexpr (AF32) {
      float4 a0[4], a1[4];
#pragma unroll
      for (int c = 0; c < 4; ++c) {
        const float* ap = Ab32 + (size_t)c * 32 * KD + kt;
        a0[c] = *(const float4*)ap;
        a1[c] = *(const float4*)(ap + 4);
        GLD16(Bb + (size_t)c * 32 * KD + kt, lB + c * 4096);
      }
      asm volatile("s_waitcnt vmcnt(0)" ::: "memory");
#pragma unroll
      for (int c = 0; c < 4; ++c) {
        union { unsigned u[4]; u16v8 v; } pk;
        pk.u[0] = cvtpk(a0[c].x, a0[c].y);
        pk.u[1] = cvtpk(a0[c].z, a0[c].w);
        pk.u[2] = cvtpk(a1[c].x, a1[c].y);
        pk.u[3] = cvtpk(a1[c].z, a1[c].w);
        *(u16v8*)(lA + c * 4096) = pk.v;
      }
    } else {
#pragma unroll
      for (int c = 0; c < 4; ++c) {
        GLD16(Ab16 + (size_t)c * 32 * KD + kt, lA + c * 4096);
        GLD16(Bb + (size_t)c * 32 * KD + kt, lB + c * 4096);
      }
      asm volatile("s_waitcnt vmcnt(0)" ::: "memory");
    }
    __syncthreads();
#pragma unroll
    for (int kk = 0; kk < 2; ++kk) {
      bf8 av[4], bv[4];
#pragma unroll
      for (int m = 0; m < 4; ++m) {
        int row = wm * 64 + m * 16 + i;
        int colb = (kk * 64 + g * 16) ^ ((row & 7) << 4);
        av[m] = *(const bf8*)((const char*)As + row * 128 + colb);
      }
#pragma unroll
      for (int n = 0; n < 4; ++n) {
        int row = wn * 64 + n * 16 + i;
        int colb = (kk * 64 + g * 16) ^ ((row & 7) << 4);
        bv[n] = *(const bf8*)((const char*)Bs + row * 128 + colb);
      }
      __builtin_amdgcn_s_setprio(1);
#pragma unroll
      for (int m = 0; m < 4; ++m)
#pragma unroll
        for (int n = 0; n < 4; ++n)
          acc[m][n] = MFMA(av[m], bv[n], acc[m][n]);
      __builtin_amdgcn_s_setprio(0);
    }
  }

  const int rowb = bm * 128 + wm * 64 + g * 4;  // + m*16 + r
  const int colb = bn * 128 + wn * 64 + i;      // + n*16
  if (mode == 0) {
    unsigned short* Cb = (unsigned short*)C;
#pragma unroll
    for (int m = 0; m < 4; ++m)
#pragma unroll
      for (int n = 0; n < 4; ++n)
#pragma unroll
        for (int r = 0; r < 4; ++r)
          Cb[(size_t)(rowb + m * 16 + r) * N + colb + n * 16] = f2bf(acc[m][n][r]);
  } else if (mode == 1) {
    float* Cf = (float*)C;
#pragma unroll
    for (int m = 0; m < 4; ++m)
#pragma unroll
      for (int n = 0; n < 4; ++n)
#pragma unroll
        for (int r = 0; r < 4; ++r)
          Cf[(size_t)(rowb + m * 16 + r) * N + colb + n * 16] = acc[m][n][r];
  } else {
    // Vt[(b*512 + n_global)*2048 + sigma^-1(s)]: within each 32-key block,
    // slot k holds V_true[sigma(k)], sigma(k) = (k&3)|((k>>3)&3)<<2|((k>>2)&1)<<4.
    // sigma^-1 preserves bits 0,1 -> the 4-consecutive-s block stays one 8B store.
    unsigned short* Vt = (unsigned short*)C;
#pragma unroll
    for (int m = 0; m < 4; ++m) {
      int mg = rowb + m * 16;
      int bidx = mg >> 11, s = mg & 2047;
      int s2 = (s & ~28) | ((s & 16) >> 2) | ((s & 12) << 1);  // sigma^-1
#pragma unroll
      for (int n = 0; n < 4; ++n) {
        int col = colb + n * 16;
        u16v4 v;
        v[0] = f2bf(acc[m][n][0]); v[1] = f2bf(acc[m][n][1]);
        v[2] = f2bf(acc[m][n][2]); v[3] = f2bf(acc[m][n][3]);
        *(u16v4*)&Vt[((size_t)bidx * 512 + col) * 2048 + s2] = v;
      }
    }
  }
}

// fused Q/K/V projection GEMMs with inline f32->bf16 A conversion
__global__ __launch_bounds__(256) void k_gemm_qkv(
    const float* __restrict__ Qf, const float* __restrict__ Kf,
    const float* __restrict__ Vf, const unsigned short* __restrict__ BtQ,
    const unsigned short* __restrict__ BtK, const unsigned short* __restrict__ BtV,
    unsigned short* __restrict__ Ql, unsigned short* __restrict__ Kw,
    unsigned short* __restrict__ Vt) {
  int z = blockIdx.z;
  const float* A = z == 0 ? Qf : z == 1 ? Kf : Vf;
  const unsigned short* Bt = z == 0 ? BtQ : z == 1 ? BtK : BtV;
  void* C = z == 0 ? (void*)Ql : z == 1 ? (void*)Kw : (void*)Vt;
  gemm_body<true>(A, Bt, C, z == 2 ? 2 : 0);
}

__global__ __launch_bounds__(256) void k_gemm_out(const unsigned short* __restrict__ A,
                                                  const unsigned short* __restrict__ Bt,
                                                  void* __restrict__ C) {
  gemm_body<false>(A, Bt, C, 1);
}

// ---------- flash attention: 16x16x32 MFMA, P in-register, split-KV ----------
// grid (16 qblocks, 32 bh); 512 threads = 2 KV-groups x 4 waves x 32 q-rows.
// Swapped QK^T: lane (i,g) holds sv[kf][r] = P[key=kf*16+g*4+r][q=i]; feeds PV's
// A-operand directly via the sigma slot map (V key axis pre-permuted in the Vt
// GEMM epilogue) -> no P LDS, no cross-lane ops. No-max exp2 softmax (log2e
// folded into K weights); split-KV partials (O,L) merged through LDS.
// K/V staged via global_load_lds (m97 structure): double-buffered, loads for
// tile t+2 issued right after the tile-t barrier -> full compute phase of
// latency cover; one vmcnt(0)+barrier per tile; no reg round-trip.
// Source col inverse-swizzled (rule #21): dest linear base+lane*16 -> row =
// (w*2+c)*8 + (lane>>3), src elem col = ((lane&7)^(lane>>3))*8.
// NOTE: min-waves/EU = 4 (VGPR cap 128); 6 caused a 1 GB scratch spill (R11).
// R13: no-LDS frag reads = 135 us (latency-bound). R14: single-barrier with
// reg-staged writes-after-compute = 53 us (writes on critical path).
__global__ __launch_bounds__(512, 4) void k_attn(const unsigned short* __restrict__ Ql,
                                                 const unsigned short* __restrict__ Kw,
                                                 const unsigned short* __restrict__ Vt,
                                                 unsigned short* __restrict__ Hd) {
  __shared__ char pool[65536];  // per group: K0,K1,V0,V1 x 8KB; epilogue aliases
  const int t = threadIdx.x, lane = t & 63, wv = t >> 6;
  const int grp = wv >> 2, w = wv & 3;
  const int i = lane & 15, g = lane >> 4;
  const int qb = blockIdx.x, bh = blockIdx.y;
  const int b = bh >> 3, h = bh & 7;

  char* K0 = pool + grp * 32768;  // [64 key][64 d] bf16, XOR-swizzled
  char* K1 = K0 + 8192;
  char* V0 = K0 + 16384;          // [64 d][64 keyslot] bf16, XOR-swizzled
  char* V1 = K0 + 24576;

  // Q fragments: this wave's q-rows are qb*128 + w*32 + m*16 + i
  bf8 qf[2][2];
#pragma unroll
  for (int m = 0; m < 2; ++m) {
    const unsigned short* Qrow =
        Ql + ((size_t)(b * 2048 + qb * 128 + w * 32 + m * 16 + i)) * 512 + h * 64;
#pragma unroll
    for (int kc = 0; kc < 2; ++kc) qf[m][kc] = *(const bf8*)&Qrow[kc * 32 + g * 8];
  }

  const unsigned short* Kbase = Kw + ((size_t)b * 2048) * 512 + h * 64;
  const unsigned short* Vbase = Vt + (size_t)bh * 64 * 2048;
  const int kv0 = grp * 1024;

  // gload_lds staging coords: dest linear (w*2+c)*1024 + lane*16 within buffer;
  // row = w*16 + c*8 + (lane>>3); source elem col inverse-swizzled.
  const int r8 = lane >> 3;
  const int se2 = ((lane & 7) ^ r8) * 8;
  const int rK0 = w * 16 + r8, rK1 = rK0 + 8;
  char* dst0;  // set per STAGE via buffer base

#define STAGE(KB, VB, kvv)                                                     \
  do {                                                                         \
    GLD16(Kbase + (size_t)((kvv) + rK0) * 512 + se2, (KB) + w * 2048 + lane * 16);        \
    GLD16(Kbase + (size_t)((kvv) + rK1) * 512 + se2, (KB) + w * 2048 + 1024 + lane * 16); \
    GLD16(Vbase + (size_t)rK0 * 2048 + (kvv) + se2, (VB) + w * 2048 + lane * 16);         \
    GLD16(Vbase + (size_t)rK1 * 2048 + (kvv) + se2, (VB) + w * 2048 + 1024 + lane * 16);  \
  } while (0)

#define COMPUTE(KB, VB)                                                        \
  do {                                                                         \
    f4 sv0[4] = {}, sv1[4] = {};                                               \
    __builtin_amdgcn_s_setprio(1);                                             \
    _Pragma("unroll") for (int kf = 0; kf < 4; ++kf) {                         \
      const char* kp = (KB) + (kf * 16 + i) * 128;                             \
      _Pragma("unroll") for (int kc = 0; kc < 2; ++kc) {                       \
        bf8 kfr = *(const bf8*)(kp + ((kc * 64 + g * 16) ^ xi));               \
        sv0[kf] = MFMA(kfr, qf[0][kc], sv0[kf]);                               \
        sv1[kf] = MFMA(kfr, qf[1][kc], sv1[kf]);                               \
      }                                                                        \
    }                                                                          \
    __builtin_amdgcn_s_setprio(0);                                             \
    _Pragma("unroll") for (int kf = 0; kf < 4; ++kf)                           \
        _Pragma("unroll") for (int r = 0; r < 4; ++r) {                        \
      float p0 = exp2a(sv0[kf][r]); sv0[kf][r] = p0; Lx0 += p0;                \
      float p1 = exp2a(sv1[kf][r]); sv1[kf][r] = p1; Lx1 += p1;                \
    }                                                                          \
    __builtin_amdgcn_s_setprio(1);                                             \
    _Pragma("unroll") for (int kc = 0; kc < 2; ++kc) {                         \
      union { unsigned u[4]; bf8 v; } p0, p1;                                  \
      p0.u[0] = cvtpk(sv0[2 * kc][0], sv0[2 * kc][1]);                         \
      p0.u[1] = cvtpk(sv0[2 * kc][2], sv0[2 * kc][3]);                         \
      p0.u[2] = cvtpk(sv0[2 * kc + 1][0], sv0[2 * kc + 1][1]);                 \
      p0.u[3] = cvtpk(sv0[2 * kc + 1][2], sv0[2 * kc + 1][3]);                 \
      p1.u[0] = cvtpk(sv1[2 * kc][0], sv1[2 * kc][1]);                         \
      p1.u[1] = cvtpk(sv1[2 * kc][2], sv1[2 * kc][3]);                         \
      p1.u[2] = cvtpk(sv1[2 * kc + 1][0], sv1[2 * kc + 1][1]);                 \
      p1.u[3] = cvtpk(sv1[2 * kc + 1][2], sv1[2 * kc + 1][3]);                 \
      _Pragma("unroll") for (int n = 0; n < 4; ++n) {                          \
        const char* vp = (VB) + (n * 16 + i) * 128;                            \
        bf8 vfr = *(const bf8*)(vp + ((kc * 64 + g * 16) ^ xi));               \
        oacc[0][n] = MFMA(p0.v, vfr, oacc[0][n]);                              \
        oacc[1][n] = MFMA(p1.v, vfr, oacc[1][n]);                              \
      }                                                                        \
    }                                                                          \
    __builtin_amdgcn_s_setprio(0);                                             \
  } while (0)

  f4 oacc[2][4] = {};          // O[m][q=g*4+r][d=n*16+i]
  float Lx0 = 0.f, Lx1 = 0.f;  // per-lane exp2 partial sums, subtile 0/1
  const int xi = (i & 7) << 4;

  STAGE(K0, V0, kv0);
  asm volatile("s_waitcnt vmcnt(0)" ::: "memory");
  __syncthreads();
  STAGE(K1, V1, kv0 + 64);  // tile 1 in flight under tile-0 compute

  for (int it2 = 0; it2 < 8; ++it2) {
    COMPUTE(K0, V0);
    asm volatile("s_waitcnt vmcnt(0)" ::: "memory");  // tile 2*it2+1 landed
    __syncthreads();                                  // all waves done with K0/V0
    if (it2 < 7) STAGE(K0, V0, kv0 + (it2 * 2 + 2) * 64);
    COMPUTE(K1, V1);
    asm volatile("s_waitcnt vmcnt(0)" ::: "memory");
    __syncthreads();
    if (it2 < 7) STAGE(K1, V1, kv0 + (it2 * 2 + 3) * 64);
  }
#undef STAGE
#undef COMPUTE

  // reduce L across g-groups (all lanes end with L(q = m*16 + i))
  Lx0 += __shfl_xor(Lx0, 16);
  Lx0 += __shfl_xor(Lx0, 32);
  Lx1 += __shfl_xor(Lx1, 16);
  Lx1 += __shfl_xor(Lx1, 32);

  // merge the two KV-half partials through LDS (loop-end barrier already done)
  float* Of = (float*)pool;             // [128 q][68 d] f32 = 34816 B
  float* Ll = (float*)(pool + 34816);   // [128] f32
  if (grp == 1) {
#pragma unroll
    for (int m = 0; m < 2; ++m)
#pragma unroll
      for (int n = 0; n < 4; ++n)
#pragma unroll
        for (int r = 0; r < 4; ++r)
          Of[(w * 32 + m * 16 + g * 4 + r) * 68 + n * 16 + i] = oacc[m][n][r];
    if (g == 0) {
      Ll[w * 32 + i] = Lx0;
      Ll[w * 32 + 16 + i] = Lx1;
    }
  }
  __syncthreads();
  if (grp == 0) {
    float Ls0 = Lx0 + Ll[w * 32 + i];
    float Ls1 = Lx1 + Ll[w * 32 + 16 + i];
    unsigned short* Hb = Hd + ((size_t)(b * 2048 + qb * 128 + w * 32)) * 512 + h * 64;
#pragma unroll
    for (int m = 0; m < 2; ++m) {
      float Lb[4];
#pragma unroll
      for (int r = 0; r < 4; ++r)
        Lb[r] = __shfl(m == 0 ? Ls0 : Ls1, g * 4 + r);  // lane g*4+r has i==g*4+r
#pragma unroll
      for (int n = 0; n < 4; ++n)
#pragma unroll
        for (int r = 0; r < 4; ++r) {
          float o = oacc[m][n][r] + Of[(w * 32 + m * 16 + g * 4 + r) * 68 + n * 16 + i];
          Hb[(size_t)(m * 16 + g * 4 + r) * 512 + n * 16 + i] = f2bf(o / Lb[r]);
        }
    }
  }
}

extern "C" void kernel_launch(void* const* d_in, const int* in_sizes, int n_in,
                              void* d_out, int out_size, void* d_ws, size_t ws_size,
                              hipStream_t stream) {
  const float* Q = (const float*)d_in[0];
  const float* K = (const float*)d_in[1];
  const float* V = (const float*)d_in[2];
  // d_in[3] = M (unused by the layer)
  const float* WQ = (const float*)d_in[4];
  const float* WK = (const float*)d_in[5];
  const float* WV = (const float*)d_in[6];
  const float* Wg = (const float*)d_in[7];
  const float* Wmh = (const float*)d_in[8];

  char* ws = (char*)d_ws;
  const size_t MB = (size_t)1 << 20;
  unsigned short* Head = (unsigned short*)(ws + 0 * MB);  // 8MB
  unsigned short* Ql  = (unsigned short*)(ws + 24 * MB);  // 8MB
  unsigned short* Kw  = (unsigned short*)(ws + 32 * MB);  // 8MB
  unsigned short* Vt  = (unsigned short*)(ws + 40 * MB);  // 8MB
  unsigned short* BtQ = (unsigned short*)(ws + 48 * MB);
  unsigned short* BtK = (unsigned short*)(ws + 48 * MB + 512 * 1024);
  unsigned short* BtV = (unsigned short*)(ws + 49 * MB);
  unsigned short* BtM = (unsigned short*)(ws + 49 * MB + 512 * 1024);

  k_prep<<<1024, 256, 0, stream>>>(WQ, WK, WV, Wg, Wmh, BtQ, BtK, BtV, BtM);

  k_gemm_qkv<<<dim3(64, 4, 3), 256, 0, stream>>>(Q, K, V, BtQ, BtK, BtV, Ql, Kw, Vt);

  k_attn<<<dim3(16, 32), 512, 0, stream>>>(Ql, Kw, Vt, Head);

  k_gemm_out<<<dim3(64, 4), 256, 0, stream>>>(Head, BtM, d_out);
}

// Round 16
// 100.388 us; speedup vs baseline: 1.1020x; 1.1020x over previous
//
#include <hip/hip_runtime.h>
#include <math.h>

// Problem constants: B=4, S=2048, D=512, H=8, DH=64
typedef __attribute__((ext_vector_type(8))) short bf8;
typedef __attribute__((ext_vector_type(4))) float f4;
typedef __attribute__((ext_vector_type(8))) unsigned short u16v8;
typedef __attribute__((ext_vector_type(4))) unsigned short u16v4;

#define MFMA(a, b, c) __builtin_amdgcn_mfma_f32_16x16x32_bf16((a), (b), (c), 0, 0, 0)
#define GLD16(src, dst)                                                        \
  __builtin_amdgcn_global_load_lds((const __attribute__((address_space(1))) void*)(src), \
                                   (__attribute__((address_space(3))) void*)(dst), 16, 0, 0)

__device__ __forceinline__ unsigned short f2bf(float f) {
  union { float f; unsigned u; } v; v.f = f;
  unsigned r = v.u + 0x7FFFu + ((v.u >> 16) & 1u);  // RNE
  return (unsigned short)(r >> 16);
}

__device__ __forceinline__ unsigned cvtpk(float lo, float hi) {
  unsigned r;
  asm("v_cvt_pk_bf16_f32 %0, %1, %2" : "=v"(r) : "v"(lo), "v"(hi));
  return r;
}

__device__ __forceinline__ float exp2a(float x) {  // v_exp_f32 = 2^x
  float r;
  asm("v_exp_f32 %0, %1" : "=v"(r) : "v"(x));
  return r;
}

// ---------- weight prep: transpose + bf16, fold W_gen_S (and log2e) into W_K ----------
__global__ __launch_bounds__(256) void k_prep(
    const float* __restrict__ WQ, const float* __restrict__ WK,
    const float* __restrict__ WV, const float* __restrict__ Wg,
    const float* __restrict__ Wmh,
    unsigned short* __restrict__ BtQ, unsigned short* __restrict__ BtK,
    unsigned short* __restrict__ BtV, unsigned short* __restrict__ BtM) {
  int id = blockIdx.x * 256 + threadIdx.x;  // 512*512 threads
  int k = id & 511, n = id >> 9;
  BtQ[n * 512 + k] = f2bf(WQ[k * 512 + n]);
  BtV[n * 512 + k] = f2bf(WV[k * 512 + n]);
  BtM[n * 512 + k] = f2bf(Wmh[k * 512 + n]);
  int h = n >> 6, e = n & 63;
  const float* wk = WK + k * 512 + h * 64;
  float s = 0.f;
#pragma unroll
  for (int c = 0; c < 64; ++c) s = fmaf(wk[c], Wg[c * 64 + e], s);
  BtK[n * 512 + k] = f2bf(s * 1.44269504088896f);  // fold log2(e): attn uses exp2
}

// ---------- GEMM body: C[M,512] = A[M,512] @ Bt[512,512]^T ----------
// BK=64, LDS [128][64] with XOR swizzle colb ^= (row&7)<<4 on the read side;
// A: if AF32, reg-staged f32 + cvt_pk -> ds_write to the linear slot (fused cvt);
//    else global_load_lds direct. B always global_load_lds; source pre-permuted.
// DBUF: double-buffered 2-phase pipeline (stage next tile BEFORE compute, one
//       vmcnt(0)+barrier per K-step) — for low-occupancy grids (out-GEMM 1 blk/CU).
// mode 0: bf16 row-major; 1: f32 row-major; 2: bf16 transposed-per-head (Vt),
//         with key-axis sigma^-1 pre-permutation (attn PV slot map).
template <bool AF32, bool DBUF>
__device__ __forceinline__ void gemm_body(const void* __restrict__ Av,
                                          const unsigned short* __restrict__ Bt,
                                          void* __restrict__ C, int mode) {
  constexpr int KD = 512, N = 512;
  __shared__ unsigned short As[DBUF ? 2 * 128 * 64 : 128 * 64];
  __shared__ unsigned short Bs[DBUF ? 2 * 128 * 64 : 128 * 64];
  const int t = threadIdx.x;
  const int lane = t & 63;
  const int w = t >> 6, wm = w >> 1, wn = w & 1;  // 2x2 wave grid, 64x64 per wave
  const int i = lane & 15, g = lane >> 4;
  const int bm = blockIdx.x, bn = blockIdx.y;

  f4 acc[4][4] = {};
  // staging: chunk c covers rows c*32 + (t>>3); col bytes (t&7)*16, source inverse-swizzled
  const int srow = t >> 3;
  const int scolb = (t & 7) * 16;
  const int acolb = scolb ^ ((srow & 7) << 4);
  const float* Ab32 = (const float*)Av + (size_t)(bm * 128 + srow) * KD + (acolb >> 1);
  const unsigned short* Ab16 = (const unsigned short*)Av + (size_t)(bm * 128 + srow) * KD + (acolb >> 1);
  const unsigned short* Bb = Bt + (size_t)(bn * 128 + srow) * KD + (acolb >> 1);
  char* lA = (char*)As + t * 16;
  char* lB = (char*)Bs + t * 16;

  if constexpr (DBUF && !AF32) {
    // ---- 2-phase pipeline: stage(next) || compute(cur); 1 barrier/K-step ----
#pragma unroll
    for (int c = 0; c < 4; ++c) {  // prologue: tile 0 -> buffer 0
      GLD16(Ab16 + (size_t)c * 32 * KD, lA + c * 4096);
      GLD16(Bb + (size_t)c * 32 * KD, lB + c * 4096);
    }
    asm volatile("s_waitcnt vmcnt(0)" ::: "memory");
    __syncthreads();
    for (int kt = 0, pb = 0; kt < KD; kt += 64, pb ^= 1) {
      if (kt + 64 < KD) {  // issue next tile into other buffer; flies under MFMA
        int nb = pb ^ 1;
#pragma unroll
        for (int c = 0; c < 4; ++c) {
          GLD16(Ab16 + (size_t)c * 32 * KD + kt + 64, lA + nb * 16384 + c * 4096);
          GLD16(Bb + (size_t)c * 32 * KD + kt + 64, lB + nb * 16384 + c * 4096);
        }
      }
#pragma unroll
      for (int kk = 0; kk < 2; ++kk) {
        bf8 av[4], bv[4];
#pragma unroll
        for (int m = 0; m < 4; ++m) {
          int row = wm * 64 + m * 16 + i;
          int colb = (kk * 64 + g * 16) ^ ((row & 7) << 4);
          av[m] = *(const bf8*)((const char*)As + pb * 16384 + row * 128 + colb);
        }
#pragma unroll
        for (int n = 0; n < 4; ++n) {
          int row = wn * 64 + n * 16 + i;
          int colb = (kk * 64 + g * 16) ^ ((row & 7) << 4);
          bv[n] = *(const bf8*)((const char*)Bs + pb * 16384 + row * 128 + colb);
        }
        __builtin_amdgcn_s_setprio(1);
#pragma unroll
        for (int m = 0; m < 4; ++m)
#pragma unroll
          for (int n = 0; n < 4; ++n)
            acc[m][n] = MFMA(av[m], bv[n], acc[m][n]);
        __builtin_amdgcn_s_setprio(0);
      }
      asm volatile("s_waitcnt vmcnt(0)" ::: "memory");  // next tile landed
      __syncthreads();
    }
  } else {
    for (int kt = 0; kt < KD; kt += 64) {
      __syncthreads();
      if constexpr (AF32) {
        float4 a0[4], a1[4];
#pragma unroll
        for (int c = 0; c < 4; ++c) {
          const float* ap = Ab32 + (size_t)c * 32 * KD + kt;
          a0[c] = *(const float4*)ap;
          a1[c] = *(const float4*)(ap + 4);
          GLD16(Bb + (size_t)c * 32 * KD + kt, lB + c * 4096);
        }
        asm volatile("s_waitcnt vmcnt(0)" ::: "memory");
#pragma unroll
        for (int c = 0; c < 4; ++c) {
          union { unsigned u[4]; u16v8 v; } pk;
          pk.u[0] = cvtpk(a0[c].x, a0[c].y);
          pk.u[1] = cvtpk(a0[c].z, a0[c].w);
          pk.u[2] = cvtpk(a1[c].x, a1[c].y);
          pk.u[3] = cvtpk(a1[c].z, a1[c].w);
          *(u16v8*)(lA + c * 4096) = pk.v;
        }
      } else {
#pragma unroll
        for (int c = 0; c < 4; ++c) {
          GLD16(Ab16 + (size_t)c * 32 * KD + kt, lA + c * 4096);
          GLD16(Bb + (size_t)c * 32 * KD + kt, lB + c * 4096);
        }
        asm volatile("s_waitcnt vmcnt(0)" ::: "memory");
      }
      __syncthreads();
#pragma unroll
      for (int kk = 0; kk < 2; ++kk) {
        bf8 av[4], bv[4];
#pragma unroll
        for (int m = 0; m < 4; ++m) {
          int row = wm * 64 + m * 16 + i;
          int colb = (kk * 64 + g * 16) ^ ((row & 7) << 4);
          av[m] = *(const bf8*)((const char*)As + row * 128 + colb);
        }
#pragma unroll
        for (int n = 0; n < 4; ++n) {
          int row = wn * 64 + n * 16 + i;
          int colb = (kk * 64 + g * 16) ^ ((row & 7) << 4);
          bv[n] = *(const bf8*)((const char*)Bs + row * 128 + colb);
        }
        __builtin_amdgcn_s_setprio(1);
#pragma unroll
        for (int m = 0; m < 4; ++m)
#pragma unroll
          for (int n = 0; n < 4; ++n)
            acc[m][n] = MFMA(av[m], bv[n], acc[m][n]);
        __builtin_amdgcn_s_setprio(0);
      }
    }
  }

  const int rowb = bm * 128 + wm * 64 + g * 4;  // + m*16 + r
  const int colb = bn * 128 + wn * 64 + i;      // + n*16
  if (mode == 0) {
    unsigned short* Cb = (unsigned short*)C;
#pragma unroll
    for (int m = 0; m < 4; ++m)
#pragma unroll
      for (int n = 0; n < 4; ++n)
#pragma unroll
        for (int r = 0; r < 4; ++r)
          Cb[(size_t)(rowb + m * 16 + r) * N + colb + n * 16] = f2bf(acc[m][n][r]);
  } else if (mode == 1) {
    float* Cf = (float*)C;
#pragma unroll
    for (int m = 0; m < 4; ++m)
#pragma unroll
      for (int n = 0; n < 4; ++n)
#pragma unroll
        for (int r = 0; r < 4; ++r)
          Cf[(size_t)(rowb + m * 16 + r) * N + colb + n * 16] = acc[m][n][r];
  } else {
    // Vt[(b*512 + n_global)*2048 + sigma^-1(s)]: within each 32-key block,
    // slot k holds V_true[sigma(k)], sigma(k) = (k&3)|((k>>3)&3)<<2|((k>>2)&1)<<4.
    // sigma^-1 preserves bits 0,1 -> the 4-consecutive-s block stays one 8B store.
    unsigned short* Vt = (unsigned short*)C;
#pragma unroll
    for (int m = 0; m < 4; ++m) {
      int mg = rowb + m * 16;
      int bidx = mg >> 11, s = mg & 2047;
      int s2 = (s & ~28) | ((s & 16) >> 2) | ((s & 12) << 1);  // sigma^-1
#pragma unroll
      for (int n = 0; n < 4; ++n) {
        int col = colb + n * 16;
        u16v4 v;
        v[0] = f2bf(acc[m][n][0]); v[1] = f2bf(acc[m][n][1]);
        v[2] = f2bf(acc[m][n][2]); v[3] = f2bf(acc[m][n][3]);
        *(u16v4*)&Vt[((size_t)bidx * 512 + col) * 2048 + s2] = v;
      }
    }
  }
}

// fused Q/K/V projection GEMMs with inline f32->bf16 A conversion
__global__ __launch_bounds__(256) void k_gemm_qkv(
    const float* __restrict__ Qf, const float* __restrict__ Kf,
    const float* __restrict__ Vf, const unsigned short* __restrict__ BtQ,
    const unsigned short* __restrict__ BtK, const unsigned short* __restrict__ BtV,
    unsigned short* __restrict__ Ql, unsigned short* __restrict__ Kw,
    unsigned short* __restrict__ Vt) {
  int z = blockIdx.z;
  const float* A = z == 0 ? Qf : z == 1 ? Kf : Vf;
  const unsigned short* Bt = z == 0 ? BtQ : z == 1 ? BtK : BtV;
  void* C = z == 0 ? (void*)Ql : z == 1 ? (void*)Kw : (void*)Vt;
  gemm_body<true, false>(A, Bt, C, z == 2 ? 2 : 0);
}

__global__ __launch_bounds__(256) void k_gemm_out(const unsigned short* __restrict__ A,
                                                  const unsigned short* __restrict__ Bt,
                                                  void* __restrict__ C) {
  gemm_body<false, true>(A, Bt, C, 1);  // 1 blk/CU grid -> 2-phase pipeline
}

// ---------- flash attention: 16x16x32 MFMA, P in-register, split-KV (R12) ----------
// grid (16 qblocks, 32 bh); 512 threads = 2 KV-groups x 4 waves x 32 q-rows.
// Swapped QK^T: lane (i,g) holds sv[kf][r] = P[key=kf*16+g*4+r][q=i]; feeds PV's
// A-operand directly via the sigma slot map (V key axis pre-permuted in the Vt
// GEMM epilogue) -> no P LDS, no cross-lane ops. No-max exp2 softmax (log2e
// folded into K weights); split-KV partials (O,L) merged through LDS.
// Reg-staged single-buffered K/V, 2 barriers/tile — R13/R14/R15 structural
// variants (no-LDS, write-late 1-barrier, gload_lds) ALL regressed; this is
// the verified local optimum. min-waves/EU = 4 (VGPR cap 128; 6 => 1GB spill).
__global__ __launch_bounds__(512, 4) void k_attn(const unsigned short* __restrict__ Ql,
                                                 const unsigned short* __restrict__ Kw,
                                                 const unsigned short* __restrict__ Vt,
                                                 unsigned short* __restrict__ Hd) {
  __shared__ char pool[35328];  // K/V tiles 32KB (2 grp x 16KB); epilogue Of/Ll alias
  const int t = threadIdx.x, lane = t & 63, wv = t >> 6;
  const int grp = wv >> 2, w = wv & 3;
  const int i = lane & 15, g = lane >> 4;
  const int qb = blockIdx.x, bh = blockIdx.y;
  const int b = bh >> 3, h = bh & 7;

  char* Ks = pool + grp * 8192;            // [64 key][64 d] bf16, XOR-swizzled
  char* Vs = pool + 16384 + grp * 8192;    // [64 d][64 keyslot] bf16, XOR-swizzled

  // Q fragments: this wave's q-rows are qb*128 + w*32 + m*16 + i
  bf8 qf[2][2];
#pragma unroll
  for (int m = 0; m < 2; ++m) {
    const unsigned short* Qrow =
        Ql + ((size_t)(b * 2048 + qb * 128 + w * 32 + m * 16 + i)) * 512 + h * 64;
#pragma unroll
    for (int kc = 0; kc < 2; ++kc) qf[m][kc] = *(const bf8*)&Qrow[kc * 32 + g * 8];
  }

  const unsigned short* Kbase = Kw + ((size_t)b * 2048) * 512 + h * 64;
  const unsigned short* Vbase = Vt + (size_t)bh * 64 * 2048;
  const int kv0 = grp * 1024;

  // staging coords (R9-verified): 256 threads/group stage 64x64 K and V tiles
  const int tt = t & 255;
  const int sr = tt >> 3;                              // row 0..31 (+32 chunk)
  const int scb = (tt & 7) * 16;                       // linear byte col
  const int se = scb >> 1;                             // element col (source)
  const int dsw = scb ^ ((sr & 7) << 4);               // swizzled byte col (dest)
  const int d0 = sr * 128 + dsw, d1 = (sr + 32) * 128 + dsw;  // (sr+32)&7==sr&7

#define LOADSET(kvv)                                                           \
  do {                                                                         \
    kr0 = *(const u16v8*)&Kbase[(size_t)((kvv) + sr) * 512 + se];              \
    kr1 = *(const u16v8*)&Kbase[(size_t)((kvv) + 32 + sr) * 512 + se];         \
    vr0 = *(const u16v8*)&Vbase[(size_t)sr * 2048 + (kvv) + se];               \
    vr1 = *(const u16v8*)&Vbase[(size_t)(32 + sr) * 2048 + (kvv) + se];        \
  } while (0)

  u16v8 kr0, kr1, vr0, vr1;
  LOADSET(kv0);

  f4 oacc[2][4] = {};          // O[m][q=g*4+r][d=n*16+i]
  float Lx0 = 0.f, Lx1 = 0.f;  // per-lane exp2 partial sums, subtile 0/1
  const int xi = (i & 7) << 4;

  for (int it = 0; it < 16; ++it) {
    __syncthreads();  // prior tile's LDS reads complete
    *(u16v8*)(Ks + d0) = kr0;
    *(u16v8*)(Ks + d1) = kr1;
    *(u16v8*)(Vs + d0) = vr0;
    *(u16v8*)(Vs + d1) = vr1;
    __syncthreads();
    if (it < 15) LOADSET(kv0 + (it + 1) * 64);  // prefetch flies under compute

    // S^T = K_w Q^T for both q-subtiles; K-frag read once, used twice
    f4 sv0[4] = {}, sv1[4] = {};
    __builtin_amdgcn_s_setprio(1);
#pragma unroll
    for (int kf = 0; kf < 4; ++kf) {
      const char* kp = Ks + (kf * 16 + i) * 128;
#pragma unroll
      for (int kc = 0; kc < 2; ++kc) {
        bf8 kfr = *(const bf8*)(kp + ((kc * 64 + g * 16) ^ xi));
        sv0[kf] = MFMA(kfr, qf[0][kc], sv0[kf]);
        sv1[kf] = MFMA(kfr, qf[1][kc], sv1[kf]);
      }
    }
    __builtin_amdgcn_s_setprio(0);

    // no-max softmax (scores bounded; exp2 with log2e folded into K weights)
#pragma unroll
    for (int kf = 0; kf < 4; ++kf)
#pragma unroll
      for (int r = 0; r < 4; ++r) {
        float p0 = exp2a(sv0[kf][r]); sv0[kf][r] = p0; Lx0 += p0;
        float p1 = exp2a(sv1[kf][r]); sv1[kf][r] = p1; Lx1 += p1;
      }

    // O += P @ V with P straight from registers:
    // A slot e = e1*4 + r holds P[key = kc*32 + e1*16 + g*4 + r] = sv[2kc+e1][r];
    // Vs key axis pre-permuted by sigma^-1 so slots line up. V-frag shared by
    // both q-subtiles.
    __builtin_amdgcn_s_setprio(1);
#pragma unroll
    for (int kc = 0; kc < 2; ++kc) {
      union { unsigned u[4]; bf8 v; } p0, p1;
      p0.u[0] = cvtpk(sv0[2 * kc][0], sv0[2 * kc][1]);
      p0.u[1] = cvtpk(sv0[2 * kc][2], sv0[2 * kc][3]);
      p0.u[2] = cvtpk(sv0[2 * kc + 1][0], sv0[2 * kc + 1][1]);
      p0.u[3] = cvtpk(sv0[2 * kc + 1][2], sv0[2 * kc + 1][3]);
      p1.u[0] = cvtpk(sv1[2 * kc][0], sv1[2 * kc][1]);
      p1.u[1] = cvtpk(sv1[2 * kc][2], sv1[2 * kc][3]);
      p1.u[2] = cvtpk(sv1[2 * kc + 1][0], sv1[2 * kc + 1][1]);
      p1.u[3] = cvtpk(sv1[2 * kc + 1][2], sv1[2 * kc + 1][3]);
#pragma unroll
      for (int n = 0; n < 4; ++n) {
        const char* vp = Vs + (n * 16 + i) * 128;
        bf8 vfr = *(const bf8*)(vp + ((kc * 64 + g * 16) ^ xi));
        oacc[0][n] = MFMA(p0.v, vfr, oacc[0][n]);
        oacc[1][n] = MFMA(p1.v, vfr, oacc[1][n]);
      }
    }
    __builtin_amdgcn_s_setprio(0);
  }
#undef LOADSET

  // reduce L across g-groups (all lanes end with L(q = m*16 + i))
  Lx0 += __shfl_xor(Lx0, 16);
  Lx0 += __shfl_xor(Lx0, 32);
  Lx1 += __shfl_xor(Lx1, 16);
  Lx1 += __shfl_xor(Lx1, 32);

  // merge the two KV-half partials through LDS
  float* Of = (float*)pool;             // [128 q][68 d] f32 = 34816 B
  float* Ll = (float*)(pool + 34816);   // [128] f32
  __syncthreads();
  if (grp == 1) {
#pragma unroll
    for (int m = 0; m < 2; ++m)
#pragma unroll
      for (int n = 0; n < 4; ++n)
#pragma unroll
        for (int r = 0; r < 4; ++r)
          Of[(w * 32 + m * 16 + g * 4 + r) * 68 + n * 16 + i] = oacc[m][n][r];
    if (g == 0) {
      Ll[w * 32 + i] = Lx0;
      Ll[w * 32 + 16 + i] = Lx1;
    }
  }
  __syncthreads();
  if (grp == 0) {
    float Ls0 = Lx0 + Ll[w * 32 + i];
    float Ls1 = Lx1 + Ll[w * 32 + 16 + i];
    unsigned short* Hb = Hd + ((size_t)(b * 2048 + qb * 128 + w * 32)) * 512 + h * 64;
#pragma unroll
    for (int m = 0; m < 2; ++m) {
      float Lb[4];
#pragma unroll
      for (int r = 0; r < 4; ++r)
        Lb[r] = __shfl(m == 0 ? Ls0 : Ls1, g * 4 + r);  // lane g*4+r has i==g*4+r
#pragma unroll
      for (int n = 0; n < 4; ++n)
#pragma unroll
        for (int r = 0; r < 4; ++r) {
          float o = oacc[m][n][r] + Of[(w * 32 + m * 16 + g * 4 + r) * 68 + n * 16 + i];
          Hb[(size_t)(m * 16 + g * 4 + r) * 512 + n * 16 + i] = f2bf(o / Lb[r]);
        }
    }
  }
}

extern "C" void kernel_launch(void* const* d_in, const int* in_sizes, int n_in,
                              void* d_out, int out_size, void* d_ws, size_t ws_size,
                              hipStream_t stream) {
  const float* Q = (const float*)d_in[0];
  const float* K = (const float*)d_in[1];
  const float* V = (const float*)d_in[2];
  // d_in[3] = M (unused by the layer)
  const float* WQ = (const float*)d_in[4];
  const float* WK = (const float*)d_in[5];
  const float* WV = (const float*)d_in[6];
  const float* Wg = (const float*)d_in[7];
  const float* Wmh = (const float*)d_in[8];

  char* ws = (char*)d_ws;
  const size_t MB = (size_t)1 << 20;
  unsigned short* Head = (unsigned short*)(ws + 0 * MB);  // 8MB
  unsigned short* Ql  = (unsigned short*)(ws + 24 * MB);  // 8MB
  unsigned short* Kw  = (unsigned short*)(ws + 32 * MB);  // 8MB
  unsigned short* Vt  = (unsigned short*)(ws + 40 * MB);  // 8MB
  unsigned short* BtQ = (unsigned short*)(ws + 48 * MB);
  unsigned short* BtK = (unsigned short*)(ws + 48 * MB + 512 * 1024);
  unsigned short* BtV = (unsigned short*)(ws + 49 * MB);
  unsigned short* BtM = (unsigned short*)(ws + 49 * MB + 512 * 1024);

  k_prep<<<1024, 256, 0, stream>>>(WQ, WK, WV, Wg, Wmh, BtQ, BtK, BtV, BtM);

  k_gemm_qkv<<<dim3(64, 4, 3), 256, 0, stream>>>(Q, K, V, BtQ, BtK, BtV, Ql, Kw, Vt);

  k_attn<<<dim3(16, 32), 512, 0, stream>>>(Ql, Kw, Vt, Head);

  k_gemm_out<<<dim3(64, 4), 256, 0, stream>>>(Head, BtM, d_out);
}

// Round 17
// 92.178 us; speedup vs baseline: 1.2001x; 1.0891x over previous
//
#include <hip/hip_runtime.h>
#include <math.h>

// Problem constants: B=4, S=2048, D=512, H=8, DH=64
typedef __attribute__((ext_vector_type(8))) short bf8;
typedef __attribute__((ext_vector_type(4))) float f4;
typedef __attribute__((ext_vector_type(8))) unsigned short u16v8;
typedef __attribute__((ext_vector_type(4))) unsigned short u16v4;

#define MFMA(a, b, c) __builtin_amdgcn_mfma_f32_16x16x32_bf16((a), (b), (c), 0, 0, 0)
#define GLD16(src, dst)                                                        \
  __builtin_amdgcn_global_load_lds((const __attribute__((address_space(1))) void*)(src), \
                                   (__attribute__((address_space(3))) void*)(dst), 16, 0, 0)

__device__ __forceinline__ unsigned short f2bf(float f) {
  union { float f; unsigned u; } v; v.f = f;
  unsigned r = v.u + 0x7FFFu + ((v.u >> 16) & 1u);  // RNE
  return (unsigned short)(r >> 16);
}

__device__ __forceinline__ unsigned cvtpk(float lo, float hi) {
  unsigned r;
  asm("v_cvt_pk_bf16_f32 %0, %1, %2" : "=v"(r) : "v"(lo), "v"(hi));
  return r;
}

__device__ __forceinline__ float exp2a(float x) {  // v_exp_f32 = 2^x
  float r;
  asm("v_exp_f32 %0, %1" : "=v"(r) : "v"(x));
  return r;
}

// ---------- weight prep: transpose + bf16, fold W_gen_S (and log2e) into W_K ----------
__global__ __launch_bounds__(256) void k_prep(
    const float* __restrict__ WQ, const float* __restrict__ WK,
    const float* __restrict__ WV, const float* __restrict__ Wg,
    const float* __restrict__ Wmh,
    unsigned short* __restrict__ BtQ, unsigned short* __restrict__ BtK,
    unsigned short* __restrict__ BtV, unsigned short* __restrict__ BtM) {
  int id = blockIdx.x * 256 + threadIdx.x;  // 512*512 threads
  int k = id & 511, n = id >> 9;
  BtQ[n * 512 + k] = f2bf(WQ[k * 512 + n]);
  BtV[n * 512 + k] = f2bf(WV[k * 512 + n]);
  BtM[n * 512 + k] = f2bf(Wmh[k * 512 + n]);
  int h = n >> 6, e = n & 63;
  const float* wk = WK + k * 512 + h * 64;
  float s = 0.f;
#pragma unroll
  for (int c = 0; c < 64; ++c) s = fmaf(wk[c], Wg[c * 64 + e], s);
  BtK[n * 512 + k] = f2bf(s * 1.44269504088896f);  // fold log2(e): attn uses exp2
}

// ---------- GEMM body: C[M,512] = A[M,512] @ Bt[512,512]^T ----------
// BK=64, LDS [128][64] with XOR swizzle colb ^= (row&7)<<4 on the read side;
// A: if AF32, reg-staged f32 + cvt_pk -> ds_write to the linear slot (fused cvt);
//    else global_load_lds direct. B always global_load_lds; source pre-permuted.
// DBUF pipelines (issue next tile BEFORE compute, loads fly under MFMA):
//   DBUF && !AF32: both operands double-buffered via GLD (out-GEMM, 1 blk/CU).
//   DBUF &&  AF32: A-regs act as the A double buffer (As single, Bs double;
//                  48 KB LDS -> 3 blk/CU). compute -> barrier -> vmcnt ->
//                  cvt+write As -> barrier.
// mode 0: bf16 row-major; 1: f32 row-major; 2: bf16 transposed-per-head (Vt),
//         with key-axis sigma^-1 pre-permutation (attn PV slot map).
template <bool AF32, bool DBUF>
__device__ __forceinline__ void gemm_body(const void* __restrict__ Av,
                                          const unsigned short* __restrict__ Bt,
                                          void* __restrict__ C, int mode) {
  constexpr int KD = 512, N = 512;
  __shared__ unsigned short As[(DBUF && !AF32) ? 2 * 128 * 64 : 128 * 64];
  __shared__ unsigned short Bs[DBUF ? 2 * 128 * 64 : 128 * 64];
  const int t = threadIdx.x;
  const int lane = t & 63;
  const int w = t >> 6, wm = w >> 1, wn = w & 1;  // 2x2 wave grid, 64x64 per wave
  const int i = lane & 15, g = lane >> 4;
  const int bm = blockIdx.x, bn = blockIdx.y;

  f4 acc[4][4] = {};
  // staging: chunk c covers rows c*32 + (t>>3); col bytes (t&7)*16, source inverse-swizzled
  const int srow = t >> 3;
  const int scolb = (t & 7) * 16;
  const int acolb = scolb ^ ((srow & 7) << 4);
  const float* Ab32 = (const float*)Av + (size_t)(bm * 128 + srow) * KD + (acolb >> 1);
  const unsigned short* Ab16 = (const unsigned short*)Av + (size_t)(bm * 128 + srow) * KD + (acolb >> 1);
  const unsigned short* Bb = Bt + (size_t)(bn * 128 + srow) * KD + (acolb >> 1);
  char* lA = (char*)As + t * 16;
  char* lB = (char*)Bs + t * 16;

#define GEMM_FRAGS_AND_MFMA(ABASE, BBASE)                                      \
  do {                                                                         \
    _Pragma("unroll") for (int kk = 0; kk < 2; ++kk) {                         \
      bf8 av[4], bv[4];                                                        \
      _Pragma("unroll") for (int m = 0; m < 4; ++m) {                          \
        int row = wm * 64 + m * 16 + i;                                        \
        int colb = (kk * 64 + g * 16) ^ ((row & 7) << 4);                      \
        av[m] = *(const bf8*)((ABASE) + row * 128 + colb);                     \
      }                                                                        \
      _Pragma("unroll") for (int n = 0; n < 4; ++n) {                          \
        int row = wn * 64 + n * 16 + i;                                        \
        int colb = (kk * 64 + g * 16) ^ ((row & 7) << 4);                      \
        bv[n] = *(const bf8*)((BBASE) + row * 128 + colb);                     \
      }                                                                        \
      __builtin_amdgcn_s_setprio(1);                                           \
      _Pragma("unroll") for (int m = 0; m < 4; ++m)                            \
          _Pragma("unroll") for (int n = 0; n < 4; ++n)                        \
              acc[m][n] = MFMA(av[m], bv[n], acc[m][n]);                       \
      __builtin_amdgcn_s_setprio(0);                                           \
    }                                                                          \
  } while (0)

  if constexpr (DBUF && AF32) {
    // ---- A-regs double buffer + Bs double buffer; loads fly under compute ----
    float4 a0[4], a1[4];
#pragma unroll
    for (int c = 0; c < 4; ++c) {  // prologue: tile 0
      const float* ap = Ab32 + (size_t)c * 32 * KD;
      a0[c] = *(const float4*)ap;
      a1[c] = *(const float4*)(ap + 4);
      GLD16(Bb + (size_t)c * 32 * KD, lB + c * 4096);
    }
    asm volatile("s_waitcnt vmcnt(0)" ::: "memory");
#pragma unroll
    for (int c = 0; c < 4; ++c) {
      union { unsigned u[4]; u16v8 v; } pk;
      pk.u[0] = cvtpk(a0[c].x, a0[c].y);
      pk.u[1] = cvtpk(a0[c].z, a0[c].w);
      pk.u[2] = cvtpk(a1[c].x, a1[c].y);
      pk.u[3] = cvtpk(a1[c].z, a1[c].w);
      *(u16v8*)(lA + c * 4096) = pk.v;
    }
    __syncthreads();
    for (int kt = 0, pb = 0; kt < KD; kt += 64, pb ^= 1) {
      const bool nxt = (kt + 64 < KD);
      if (nxt) {  // issue next tile's loads; they fly under this tile's MFMA
#pragma unroll
        for (int c = 0; c < 4; ++c) {
          const float* ap = Ab32 + (size_t)c * 32 * KD + kt + 64;
          a0[c] = *(const float4*)ap;
          a1[c] = *(const float4*)(ap + 4);
          GLD16(Bb + (size_t)c * 32 * KD + kt + 64, lB + (pb ^ 1) * 16384 + c * 4096);
        }
      }
      GEMM_FRAGS_AND_MFMA((const char*)As, (const char*)Bs + pb * 16384);
      __syncthreads();  // all waves done reading As (tile t)
      if (nxt) {
        asm volatile("s_waitcnt vmcnt(0)" ::: "memory");  // A-regs + B landed
#pragma unroll
        for (int c = 0; c < 4; ++c) {
          union { unsigned u[4]; u16v8 v; } pk;
          pk.u[0] = cvtpk(a0[c].x, a0[c].y);
          pk.u[1] = cvtpk(a0[c].z, a0[c].w);
          pk.u[2] = cvtpk(a1[c].x, a1[c].y);
          pk.u[3] = cvtpk(a1[c].z, a1[c].w);
          *(u16v8*)(lA + c * 4096) = pk.v;
        }
      }
      __syncthreads();  // As(t+1) + Bs[other] ready
    }
  } else if constexpr (DBUF && !AF32) {
    // ---- 2-phase pipeline: stage(next) || compute(cur); 1 barrier/K-step ----
#pragma unroll
    for (int c = 0; c < 4; ++c) {  // prologue: tile 0 -> buffer 0
      GLD16(Ab16 + (size_t)c * 32 * KD, lA + c * 4096);
      GLD16(Bb + (size_t)c * 32 * KD, lB + c * 4096);
    }
    asm volatile("s_waitcnt vmcnt(0)" ::: "memory");
    __syncthreads();
    for (int kt = 0, pb = 0; kt < KD; kt += 64, pb ^= 1) {
      if (kt + 64 < KD) {  // issue next tile into other buffer; flies under MFMA
        int nb = pb ^ 1;
#pragma unroll
        for (int c = 0; c < 4; ++c) {
          GLD16(Ab16 + (size_t)c * 32 * KD + kt + 64, lA + nb * 16384 + c * 4096);
          GLD16(Bb + (size_t)c * 32 * KD + kt + 64, lB + nb * 16384 + c * 4096);
        }
      }
      GEMM_FRAGS_AND_MFMA((const char*)As + pb * 16384, (const char*)Bs + pb * 16384);
      asm volatile("s_waitcnt vmcnt(0)" ::: "memory");  // next tile landed
      __syncthreads();
    }
  } else {
    for (int kt = 0; kt < KD; kt += 64) {
      __syncthreads();
      if constexpr (AF32) {
        float4 a0[4], a1[4];
#pragma unroll
        for (int c = 0; c < 4; ++c) {
          const float* ap = Ab32 + (size_t)c * 32 * KD + kt;
          a0[c] = *(const float4*)ap;
          a1[c] = *(const float4*)(ap + 4);
          GLD16(Bb + (size_t)c * 32 * KD + kt, lB + c * 4096);
        }
        asm volatile("s_waitcnt vmcnt(0)" ::: "memory");
#pragma unroll
        for (int c = 0; c < 4; ++c) {
          union { unsigned u[4]; u16v8 v; } pk;
          pk.u[0] = cvtpk(a0[c].x, a0[c].y);
          pk.u[1] = cvtpk(a0[c].z, a0[c].w);
          pk.u[2] = cvtpk(a1[c].x, a1[c].y);
          pk.u[3] = cvtpk(a1[c].z, a1[c].w);
          *(u16v8*)(lA + c * 4096) = pk.v;
        }
      } else {
#pragma unroll
        for (int c = 0; c < 4; ++c) {
          GLD16(Ab16 + (size_t)c * 32 * KD + kt, lA + c * 4096);
          GLD16(Bb + (size_t)c * 32 * KD + kt, lB + c * 4096);
        }
        asm volatile("s_waitcnt vmcnt(0)" ::: "memory");
      }
      __syncthreads();
      GEMM_FRAGS_AND_MFMA((const char*)As, (const char*)Bs);
    }
  }
#undef GEMM_FRAGS_AND_MFMA

  const int rowb = bm * 128 + wm * 64 + g * 4;  // + m*16 + r
  const int colb = bn * 128 + wn * 64 + i;      // + n*16
  if (mode == 0) {
    unsigned short* Cb = (unsigned short*)C;
#pragma unroll
    for (int m = 0; m < 4; ++m)
#pragma unroll
      for (int n = 0; n < 4; ++n)
#pragma unroll
        for (int r = 0; r < 4; ++r)
          Cb[(size_t)(rowb + m * 16 + r) * N + colb + n * 16] = f2bf(acc[m][n][r]);
  } else if (mode == 1) {
    float* Cf = (float*)C;
#pragma unroll
    for (int m = 0; m < 4; ++m)
#pragma unroll
      for (int n = 0; n < 4; ++n)
#pragma unroll
        for (int r = 0; r < 4; ++r)
          Cf[(size_t)(rowb + m * 16 + r) * N + colb + n * 16] = acc[m][n][r];
  } else {
    // Vt[(b*512 + n_global)*2048 + sigma^-1(s)]: within each 32-key block,
    // slot k holds V_true[sigma(k)], sigma(k) = (k&3)|((k>>3)&3)<<2|((k>>2)&1)<<4.
    // sigma^-1 preserves bits 0,1 -> the 4-consecutive-s block stays one 8B store.
    unsigned short* Vt = (unsigned short*)C;
#pragma unroll
    for (int m = 0; m < 4; ++m) {
      int mg = rowb + m * 16;
      int bidx = mg >> 11, s = mg & 2047;
      int s2 = (s & ~28) | ((s & 16) >> 2) | ((s & 12) << 1);  // sigma^-1
#pragma unroll
      for (int n = 0; n < 4; ++n) {
        int col = colb + n * 16;
        u16v4 v;
        v[0] = f2bf(acc[m][n][0]); v[1] = f2bf(acc[m][n][1]);
        v[2] = f2bf(acc[m][n][2]); v[3] = f2bf(acc[m][n][3]);
        *(u16v4*)&Vt[((size_t)bidx * 512 + col) * 2048 + s2] = v;
      }
    }
  }
}

// fused Q/K/V projection GEMMs with inline f32->bf16 A conversion + pipeline
__global__ __launch_bounds__(256, 3) void k_gemm_qkv(
    const float* __restrict__ Qf, const float* __restrict__ Kf,
    const float* __restrict__ Vf, const unsigned short* __restrict__ BtQ,
    const unsigned short* __restrict__ BtK, const unsigned short* __restrict__ BtV,
    unsigned short* __restrict__ Ql, unsigned short* __restrict__ Kw,
    unsigned short* __restrict__ Vt) {
  int z = blockIdx.z;
  const float* A = z == 0 ? Qf : z == 1 ? Kf : Vf;
  const unsigned short* Bt = z == 0 ? BtQ : z == 1 ? BtK : BtV;
  void* C = z == 0 ? (void*)Ql : z == 1 ? (void*)Kw : (void*)Vt;
  gemm_body<true, true>(A, Bt, C, z == 2 ? 2 : 0);
}

__global__ __launch_bounds__(256) void k_gemm_out(const unsigned short* __restrict__ A,
                                                  const unsigned short* __restrict__ Bt,
                                                  void* __restrict__ C) {
  gemm_body<false, true>(A, Bt, C, 1);  // 1 blk/CU grid -> 2-phase pipeline
}

// ---------- flash attention: 16x16x32 MFMA, P in-register, split-KV (R12) ----------
// grid (16 qblocks, 32 bh) with XCD-aware remap: work=(p&7)*64+(p>>3) so each
// XCD owns 4 bh (its K/V working set ~4MB = one L2). 512 threads = 2 KV-groups
// x 4 waves x 32 q-rows. Swapped QK^T: lane (i,g) holds sv[kf][r] =
// P[key=kf*16+g*4+r][q=i]; feeds PV's A-operand directly via the sigma slot map
// (V key axis pre-permuted in the Vt GEMM epilogue) -> no P LDS, no cross-lane.
// No-max exp2 softmax (log2e folded into K weights); split-KV partials merged
// through LDS. Reg-staged single-buffered K/V, 2 barriers/tile — R13/R14/R15
// variants all regressed; this is the verified local optimum.
// min-waves/EU = 4 (VGPR cap 128; 6 => 1GB spill, R11).
__global__ __launch_bounds__(512, 4) void k_attn(const unsigned short* __restrict__ Ql,
                                                 const unsigned short* __restrict__ Kw,
                                                 const unsigned short* __restrict__ Vt,
                                                 unsigned short* __restrict__ Hd) {
  __shared__ char pool[35328];  // K/V tiles 32KB (2 grp x 16KB); epilogue Of/Ll alias
  const int t = threadIdx.x, lane = t & 63, wv = t >> 6;
  const int grp = wv >> 2, w = wv & 3;
  const int i = lane & 15, g = lane >> 4;
  const int p = blockIdx.y * 16 + blockIdx.x;  // dispatch slot (x-fastest)
  const int wk = (p & 7) * 64 + (p >> 3);      // bijective XCD remap
  const int qb = wk & 15, bh = wk >> 4;
  const int b = bh >> 3, h = bh & 7;

  char* Ks = pool + grp * 8192;            // [64 key][64 d] bf16, XOR-swizzled
  char* Vs = pool + 16384 + grp * 8192;    // [64 d][64 keyslot] bf16, XOR-swizzled

  // Q fragments: this wave's q-rows are qb*128 + w*32 + m*16 + i
  bf8 qf[2][2];
#pragma unroll
  for (int m = 0; m < 2; ++m) {
    const unsigned short* Qrow =
        Ql + ((size_t)(b * 2048 + qb * 128 + w * 32 + m * 16 + i)) * 512 + h * 64;
#pragma unroll
    for (int kc = 0; kc < 2; ++kc) qf[m][kc] = *(const bf8*)&Qrow[kc * 32 + g * 8];
  }

  const unsigned short* Kbase = Kw + ((size_t)b * 2048) * 512 + h * 64;
  const unsigned short* Vbase = Vt + (size_t)bh * 64 * 2048;
  const int kv0 = grp * 1024;

  // staging coords (R9-verified): 256 threads/group stage 64x64 K and V tiles
  const int tt = t & 255;
  const int sr = tt >> 3;                              // row 0..31 (+32 chunk)
  const int scb = (tt & 7) * 16;                       // linear byte col
  const int se = scb >> 1;                             // element col (source)
  const int dsw = scb ^ ((sr & 7) << 4);               // swizzled byte col (dest)
  const int d0 = sr * 128 + dsw, d1 = (sr + 32) * 128 + dsw;  // (sr+32)&7==sr&7

#define LOADSET(kvv)                                                           \
  do {                                                                         \
    kr0 = *(const u16v8*)&Kbase[(size_t)((kvv) + sr) * 512 + se];              \
    kr1 = *(const u16v8*)&Kbase[(size_t)((kvv) + 32 + sr) * 512 + se];         \
    vr0 = *(const u16v8*)&Vbase[(size_t)sr * 2048 + (kvv) + se];               \
    vr1 = *(const u16v8*)&Vbase[(size_t)(32 + sr) * 2048 + (kvv) + se];        \
  } while (0)

  u16v8 kr0, kr1, vr0, vr1;
  LOADSET(kv0);

  f4 oacc[2][4] = {};          // O[m][q=g*4+r][d=n*16+i]
  float Lx0 = 0.f, Lx1 = 0.f;  // per-lane exp2 partial sums, subtile 0/1
  const int xi = (i & 7) << 4;

  for (int it = 0; it < 16; ++it) {
    __syncthreads();  // prior tile's LDS reads complete
    *(u16v8*)(Ks + d0) = kr0;
    *(u16v8*)(Ks + d1) = kr1;
    *(u16v8*)(Vs + d0) = vr0;
    *(u16v8*)(Vs + d1) = vr1;
    __syncthreads();
    if (it < 15) LOADSET(kv0 + (it + 1) * 64);  // prefetch flies under compute

    // S^T = K_w Q^T for both q-subtiles; K-frag read once, used twice
    f4 sv0[4] = {}, sv1[4] = {};
    __builtin_amdgcn_s_setprio(1);
#pragma unroll
    for (int kf = 0; kf < 4; ++kf) {
      const char* kp = Ks + (kf * 16 + i) * 128;
#pragma unroll
      for (int kc = 0; kc < 2; ++kc) {
        bf8 kfr = *(const bf8*)(kp + ((kc * 64 + g * 16) ^ xi));
        sv0[kf] = MFMA(kfr, qf[0][kc], sv0[kf]);
        sv1[kf] = MFMA(kfr, qf[1][kc], sv1[kf]);
      }
    }
    __builtin_amdgcn_s_setprio(0);

    // no-max softmax (scores bounded; exp2 with log2e folded into K weights)
#pragma unroll
    for (int kf = 0; kf < 4; ++kf)
#pragma unroll
      for (int r = 0; r < 4; ++r) {
        float p0 = exp2a(sv0[kf][r]); sv0[kf][r] = p0; Lx0 += p0;
        float p1 = exp2a(sv1[kf][r]); sv1[kf][r] = p1; Lx1 += p1;
      }

    // O += P @ V with P straight from registers:
    // A slot e = e1*4 + r holds P[key = kc*32 + e1*16 + g*4 + r] = sv[2kc+e1][r];
    // Vs key axis pre-permuted by sigma^-1 so slots line up. V-frag shared by
    // both q-subtiles.
    __builtin_amdgcn_s_setprio(1);
#pragma unroll
    for (int kc = 0; kc < 2; ++kc) {
      union { unsigned u[4]; bf8 v; } p0, p1;
      p0.u[0] = cvtpk(sv0[2 * kc][0], sv0[2 * kc][1]);
      p0.u[1] = cvtpk(sv0[2 * kc][2], sv0[2 * kc][3]);
      p0.u[2] = cvtpk(sv0[2 * kc + 1][0], sv0[2 * kc + 1][1]);
      p0.u[3] = cvtpk(sv0[2 * kc + 1][2], sv0[2 * kc + 1][3]);
      p1.u[0] = cvtpk(sv1[2 * kc][0], sv1[2 * kc][1]);
      p1.u[1] = cvtpk(sv1[2 * kc][2], sv1[2 * kc][3]);
      p1.u[2] = cvtpk(sv1[2 * kc + 1][0], sv1[2 * kc + 1][1]);
      p1.u[3] = cvtpk(sv1[2 * kc + 1][2], sv1[2 * kc + 1][3]);
#pragma unroll
      for (int n = 0; n < 4; ++n) {
        const char* vp = Vs + (n * 16 + i) * 128;
        bf8 vfr = *(const bf8*)(vp + ((kc * 64 + g * 16) ^ xi));
        oacc[0][n] = MFMA(p0.v, vfr, oacc[0][n]);
        oacc[1][n] = MFMA(p1.v, vfr, oacc[1][n]);
      }
    }
    __builtin_amdgcn_s_setprio(0);
  }
#undef LOADSET

  // reduce L across g-groups (all lanes end with L(q = m*16 + i))
  Lx0 += __shfl_xor(Lx0, 16);
  Lx0 += __shfl_xor(Lx0, 32);
  Lx1 += __shfl_xor(Lx1, 16);
  Lx1 += __shfl_xor(Lx1, 32);

  // merge the two KV-half partials through LDS
  float* Of = (float*)pool;             // [128 q][68 d] f32 = 34816 B
  float* Ll = (float*)(pool + 34816);   // [128] f32
  __syncthreads();
  if (grp == 1) {
#pragma unroll
    for (int m = 0; m < 2; ++m)
#pragma unroll
      for (int n = 0; n < 4; ++n)
#pragma unroll
        for (int r = 0; r < 4; ++r)
          Of[(w * 32 + m * 16 + g * 4 + r) * 68 + n * 16 + i] = oacc[m][n][r];
    if (g == 0) {
      Ll[w * 32 + i] = Lx0;
      Ll[w * 32 + 16 + i] = Lx1;
    }
  }
  __syncthreads();
  if (grp == 0) {
    float Ls0 = Lx0 + Ll[w * 32 + i];
    float Ls1 = Lx1 + Ll[w * 32 + 16 + i];
    unsigned short* Hb = Hd + ((size_t)(b * 2048 + qb * 128 + w * 32)) * 512 + h * 64;
#pragma unroll
    for (int m = 0; m < 2; ++m) {
      float Lb[4];
#pragma unroll
      for (int r = 0; r < 4; ++r)
        Lb[r] = __shfl(m == 0 ? Ls0 : Ls1, g * 4 + r);  // lane g*4+r has i==g*4+r
#pragma unroll
      for (int n = 0; n < 4; ++n)
#pragma unroll
        for (int r = 0; r < 4; ++r) {
          float o = oacc[m][n][r] + Of[(w * 32 + m * 16 + g * 4 + r) * 68 + n * 16 + i];
          Hb[(size_t)(m * 16 + g * 4 + r) * 512 + n * 16 + i] = f2bf(o / Lb[r]);
        }
    }
  }
}

extern "C" void kernel_launch(void* const* d_in, const int* in_sizes, int n_in,
                              void* d_out, int out_size, void* d_ws, size_t ws_size,
                              hipStream_t stream) {
  const float* Q = (const float*)d_in[0];
  const float* K = (const float*)d_in[1];
  const float* V = (const float*)d_in[2];
  // d_in[3] = M (unused by the layer)
  const float* WQ = (const float*)d_in[4];
  const float* WK = (const float*)d_in[5];
  const float* WV = (const float*)d_in[6];
  const float* Wg = (const float*)d_in[7];
  const float* Wmh = (const float*)d_in[8];

  char* ws = (char*)d_ws;
  const size_t MB = (size_t)1 << 20;
  unsigned short* Head = (unsigned short*)(ws + 0 * MB);  // 8MB
  unsigned short* Ql  = (unsigned short*)(ws + 24 * MB);  // 8MB
  unsigned short* Kw  = (unsigned short*)(ws + 32 * MB);  // 8MB
  unsigned short* Vt  = (unsigned short*)(ws + 40 * MB);  // 8MB
  unsigned short* BtQ = (unsigned short*)(ws + 48 * MB);
  unsigned short* BtK = (unsigned short*)(ws + 48 * MB + 512 * 1024);
  unsigned short* BtV = (unsigned short*)(ws + 49 * MB);
  unsigned short* BtM = (unsigned short*)(ws + 49 * MB + 512 * 1024);

  k_prep<<<1024, 256, 0, stream>>>(WQ, WK, WV, Wg, Wmh, BtQ, BtK, BtV, BtM);

  k_gemm_qkv<<<dim3(64, 4, 3), 256, 0, stream>>>(Q, K, V, BtQ, BtK, BtV, Ql, Kw, Vt);

  k_attn<<<dim3(16, 32), 512, 0, stream>>>(Ql, Kw, Vt, Head);

  k_gemm_out<<<dim3(64, 4), 256, 0, stream>>>(Head, BtM, d_out);
}